// Round 1
// baseline (1000.931 us; speedup 1.0000x reference)
//
#include <hip/hip_runtime.h>
#include <math.h>

// ---------------- CSR build ----------------

__global__ void hist_kernel(const int* __restrict__ dst, int* __restrict__ cnt, int E) {
    int i = blockIdx.x * blockDim.x + threadIdx.x;
    if (i < E) atomicAdd(&cnt[dst[i]], 1);
}

__global__ void dinv_kernel(const int* __restrict__ cnt, float* __restrict__ dinv, int N) {
    int i = blockIdx.x * blockDim.x + threadIdx.x;
    if (i < N) dinv[i] = 1.0f / sqrtf((float)(cnt[i] + 1));  // +1 self loop
}

__global__ __launch_bounds__(1024) void scan_kernel(const int* __restrict__ cnt,
                                                    int* __restrict__ rowptr, int n) {
    __shared__ int sums[1024];
    int t = threadIdx.x;
    int chunk = (n + 1023) >> 10;
    int beg = t * chunk;
    int end = beg + chunk; if (end > n) end = n;
    int s = 0;
    for (int i = beg; i < end; ++i) s += cnt[i];
    sums[t] = s;
    __syncthreads();
    for (int off = 1; off < 1024; off <<= 1) {
        int v = (t >= off) ? sums[t - off] : 0;
        __syncthreads();
        sums[t] += v;
        __syncthreads();
    }
    int run = (t == 0) ? 0 : sums[t - 1];
    for (int i = beg; i < end; ++i) { rowptr[i] = run; run += cnt[i]; }
    if (t == 0) rowptr[n] = sums[1023];
}

__global__ void place_kernel(const int* __restrict__ src, const int* __restrict__ dst,
                             const int* __restrict__ rowptr, int* __restrict__ cursor,
                             int* __restrict__ csr, int E) {
    int i = blockIdx.x * blockDim.x + threadIdx.x;
    if (i >= E) return;
    int d = dst[i];
    int p = atomicAdd(&cursor[d], 1);
    csr[rowptr[d] + p] = src[i];
}

// ---------------- Aggregation: Y[i] = dinv[i]*(sum_{s in in(i)} dinv[s]*X[s] + dinv[i]*X[i]) ----

__global__ void agg64_kernel(const float* __restrict__ X, const int* __restrict__ rowptr,
                             const int* __restrict__ csr, const float* __restrict__ dinv,
                             float* __restrict__ Y, int N) {
    int w = blockIdx.x * (blockDim.x >> 6) + (threadIdx.x >> 6);
    int lane = threadIdx.x & 63;
    if (w >= N) return;
    int beg = rowptr[w], end = rowptr[w + 1];
    float acc = 0.f;
    for (int e = beg; e < end; ++e) {
        int s = csr[e];
        acc += dinv[s] * X[(size_t)s * 64 + lane];
    }
    float di = dinv[w];
    acc = (acc + di * X[(size_t)w * 64 + lane]) * di;
    Y[(size_t)w * 64 + lane] = acc;
}

__global__ void agg128_kernel(const float* __restrict__ Xf, const int* __restrict__ rowptr,
                              const int* __restrict__ csr, const float* __restrict__ dinv,
                              float* __restrict__ Yf, int N) {
    int w = blockIdx.x * (blockDim.x >> 6) + (threadIdx.x >> 6);
    int lane = threadIdx.x & 63;
    if (w >= N) return;
    const float2* X = (const float2*)Xf;
    float2* Y = (float2*)Yf;
    int beg = rowptr[w], end = rowptr[w + 1];
    float ax = 0.f, ay = 0.f;
    for (int e = beg; e < end; ++e) {
        int s = csr[e];
        float ws = dinv[s];
        float2 v = X[(size_t)s * 64 + lane];
        ax += ws * v.x; ay += ws * v.y;
    }
    float di = dinv[w];
    float2 sv = X[(size_t)w * 64 + lane];
    ax = (ax + di * sv.x) * di;
    ay = (ay + di * sv.y) * di;
    float2 r; r.x = ax; r.y = ay;
    Y[(size_t)w * 64 + lane] = r;
}

// ---------------- GEMM: C[M x 128] = relu(A[M x K] @ W[K x 128] + bias) ----------------

template <int K>
__global__ __launch_bounds__(256) void gemm_relu(const float* __restrict__ A,
                                                 const float* __restrict__ W,
                                                 const float* __restrict__ B,
                                                 float* __restrict__ C, int M) {
    const int BK = 32;
    __shared__ float As[BK][132];  // [k][r], padded: 16B-aligned rows
    __shared__ float Ws[BK][128];  // [k][c]

    int t = threadIdx.x;
    int tx = t & 15, ty = t >> 4;
    int row0 = blockIdx.x * 128;

    float acc[8][8];
#pragma unroll
    for (int i = 0; i < 8; ++i)
#pragma unroll
        for (int j = 0; j < 8; ++j) acc[i][j] = 0.f;

    for (int k0 = 0; k0 < K; k0 += BK) {
        // A tile: 128 rows x 32 k, store transposed As[k][r]
#pragma unroll
        for (int l = 0; l < 4; ++l) {
            int j = t + l * 256;
            int r = j >> 3, kq = j & 7;
            int gr = row0 + r; if (gr > M - 1) gr = M - 1;
            float4 v = *reinterpret_cast<const float4*>(A + (size_t)gr * K + k0 + kq * 4);
            As[kq * 4 + 0][r] = v.x;
            As[kq * 4 + 1][r] = v.y;
            As[kq * 4 + 2][r] = v.z;
            As[kq * 4 + 3][r] = v.w;
        }
        // W tile: 32 k x 128 c
#pragma unroll
        for (int l = 0; l < 4; ++l) {
            int j = t + l * 256;
            int k = j >> 5, c4 = j & 31;
            *reinterpret_cast<float4*>(&Ws[k][c4 * 4]) =
                *reinterpret_cast<const float4*>(W + (size_t)(k0 + k) * 128 + c4 * 4);
        }
        __syncthreads();
#pragma unroll
        for (int k = 0; k < BK; ++k) {
            float4 a0 = *reinterpret_cast<const float4*>(&As[k][ty * 4]);
            float4 a1 = *reinterpret_cast<const float4*>(&As[k][64 + ty * 4]);
            float4 w0 = *reinterpret_cast<const float4*>(&Ws[k][tx * 4]);
            float4 w1 = *reinterpret_cast<const float4*>(&Ws[k][64 + tx * 4]);
            float a[8] = {a0.x, a0.y, a0.z, a0.w, a1.x, a1.y, a1.z, a1.w};
            float w[8] = {w0.x, w0.y, w0.z, w0.w, w1.x, w1.y, w1.z, w1.w};
#pragma unroll
            for (int i = 0; i < 8; ++i)
#pragma unroll
                for (int j = 0; j < 8; ++j) acc[i][j] += a[i] * w[j];
        }
        __syncthreads();
    }

    // epilogue
    float bc[8];
#pragma unroll
    for (int j = 0; j < 4; ++j) { bc[j] = B[tx * 4 + j]; bc[4 + j] = B[64 + tx * 4 + j]; }
#pragma unroll
    for (int i = 0; i < 8; ++i) {
        int r = row0 + ((i < 4) ? (ty * 4 + i) : (64 + ty * 4 + i - 4));
        if (r < M) {
            float4 v0, v1;
            v0.x = fmaxf(acc[i][0] + bc[0], 0.f);
            v0.y = fmaxf(acc[i][1] + bc[1], 0.f);
            v0.z = fmaxf(acc[i][2] + bc[2], 0.f);
            v0.w = fmaxf(acc[i][3] + bc[3], 0.f);
            v1.x = fmaxf(acc[i][4] + bc[4], 0.f);
            v1.y = fmaxf(acc[i][5] + bc[5], 0.f);
            v1.z = fmaxf(acc[i][6] + bc[6], 0.f);
            v1.w = fmaxf(acc[i][7] + bc[7], 0.f);
            *reinterpret_cast<float4*>(&C[(size_t)r * 128 + tx * 4]) = v0;
            *reinterpret_cast<float4*>(&C[(size_t)r * 128 + 64 + tx * 4]) = v1;
        }
    }
}

// ---------------- Final FC: out[p] = relu(concat(HL[l0], HR[l1]) @ fcW + fcb) ----------------

__global__ void fc_kernel(const float* __restrict__ HL, const float* __restrict__ HR,
                          const int* __restrict__ label, const float* __restrict__ fcW,
                          const float* __restrict__ fcb, float* __restrict__ out, int P) {
    int w = blockIdx.x * (blockDim.x >> 6) + (threadIdx.x >> 6);
    int lane = threadIdx.x & 63;
    if (w >= P) return;
    int l0 = label[2 * w], l1 = label[2 * w + 1];
    float xl0 = HL[(size_t)l0 * 128 + lane];
    float xl1 = HL[(size_t)l0 * 128 + 64 + lane];
    float xr0 = HR[(size_t)l1 * 128 + lane];
    float xr1 = HR[(size_t)l1 * 128 + 64 + lane];
    float a0 = xl0 * fcW[lane * 2]           + xl1 * fcW[(64 + lane) * 2]
             + xr0 * fcW[(128 + lane) * 2]   + xr1 * fcW[(192 + lane) * 2];
    float a1 = xl0 * fcW[lane * 2 + 1]       + xl1 * fcW[(64 + lane) * 2 + 1]
             + xr0 * fcW[(128 + lane) * 2 + 1] + xr1 * fcW[(192 + lane) * 2 + 1];
#pragma unroll
    for (int o = 32; o; o >>= 1) {
        a0 += __shfl_xor(a0, o);
        a1 += __shfl_xor(a1, o);
    }
    if (lane == 0) {
        out[2 * w]     = fmaxf(a0 + fcb[0], 0.f);
        out[2 * w + 1] = fmaxf(a1 + fcb[1], 0.f);
    }
}

// ---------------- launch ----------------

extern "C" void kernel_launch(void* const* d_in, const int* in_sizes, int n_in,
                              void* d_out, int out_size, void* d_ws, size_t ws_size,
                              hipStream_t stream) {
    const float* x1   = (const float*)d_in[0];
    const int*   e1   = (const int*)d_in[1];
    const float* x2   = (const float*)d_in[2];
    const int*   e2   = (const int*)d_in[3];
    const int*   label= (const int*)d_in[4];
    const float* W0   = (const float*)d_in[5];
    const float* b0   = (const float*)d_in[6];
    const float* W1   = (const float*)d_in[7];
    const float* b1   = (const float*)d_in[8];
    const float* W2   = (const float*)d_in[9];
    const float* b2   = (const float*)d_in[10];
    const float* fcW  = (const float*)d_in[11];
    const float* fcb  = (const float*)d_in[12];
    float* out = (float*)d_out;

    const int N = in_sizes[0] / 64;
    const int E = in_sizes[1] / 2;
    const int P = in_sizes[4] / 2;

    char* ws = (char*)d_ws;
    size_t off = 0;
    auto alloc = [&](size_t bytes) -> void* {
        void* p = ws + off;
        off += (bytes + 255) & ~(size_t)255;
        return p;
    };
    int*   cnt    = (int*)alloc((size_t)N * 4);
    int*   rowptr = (int*)alloc((size_t)(N + 1) * 4);
    float* dinv   = (float*)alloc((size_t)N * 4);
    int*   csr    = (int*)alloc((size_t)E * 4);
    float* bufA   = (float*)alloc((size_t)N * 128 * 4);
    float* H3L    = (float*)alloc((size_t)N * 128 * 4);
    float* H3R    = (float*)alloc((size_t)N * 128 * 4);

    auto run_graph = [&](const float* x, const int* ei, float* H) {
        const int* src = ei;
        const int* dst = ei + E;
        hipMemsetAsync(cnt, 0, (size_t)N * 4, stream);
        hist_kernel<<<(E + 255) / 256, 256, 0, stream>>>(dst, cnt, E);
        dinv_kernel<<<(N + 255) / 256, 256, 0, stream>>>(cnt, dinv, N);
        scan_kernel<<<1, 1024, 0, stream>>>(cnt, rowptr, N);
        hipMemsetAsync(cnt, 0, (size_t)N * 4, stream);
        place_kernel<<<(E + 255) / 256, 256, 0, stream>>>(src, dst, rowptr, cnt, csr, E);
        // layer 0: aggregate raw x (64) then GEMM 64->128
        agg64_kernel<<<(N + 3) / 4, 256, 0, stream>>>(x, rowptr, csr, dinv, bufA, N);
        gemm_relu<64><<<(N + 127) / 128, 256, 0, stream>>>(bufA, W0, b0, H, N);
        // layer 1
        agg128_kernel<<<(N + 3) / 4, 256, 0, stream>>>(H, rowptr, csr, dinv, bufA, N);
        gemm_relu<128><<<(N + 127) / 128, 256, 0, stream>>>(bufA, W1, b1, H, N);
        // layer 2
        agg128_kernel<<<(N + 3) / 4, 256, 0, stream>>>(H, rowptr, csr, dinv, bufA, N);
        gemm_relu<128><<<(N + 127) / 128, 256, 0, stream>>>(bufA, W2, b2, H, N);
    };

    run_graph(x1, e1, H3L);
    run_graph(x2, e2, H3R);

    fc_kernel<<<(P + 3) / 4, 256, 0, stream>>>(H3L, H3R, label, fcW, fcb, out, P);
}

// Round 2
// 808.626 us; speedup vs baseline: 1.2378x; 1.2378x over previous
//
#include <hip/hip_runtime.h>
#include <math.h>

// ---------------- CSR build ----------------

__global__ void hist_kernel(const int* __restrict__ dst, int* __restrict__ cnt, int E) {
    int i = blockIdx.x * blockDim.x + threadIdx.x;
    if (i < E) atomicAdd(&cnt[dst[i]], 1);
}

__global__ void dinv_kernel(const int* __restrict__ cnt, float* __restrict__ dinv, int N) {
    int i = blockIdx.x * blockDim.x + threadIdx.x;
    if (i < N) dinv[i] = 1.0f / sqrtf((float)(cnt[i] + 1));  // +1 self loop
}

__global__ __launch_bounds__(1024) void scan_kernel(const int* __restrict__ cnt,
                                                    int* __restrict__ rowptr, int n) {
    __shared__ int sums[1024];
    int t = threadIdx.x;
    int chunk = (n + 1023) >> 10;
    int beg = t * chunk;
    int end = beg + chunk; if (end > n) end = n;
    int s = 0;
    for (int i = beg; i < end; ++i) s += cnt[i];
    sums[t] = s;
    __syncthreads();
    for (int off = 1; off < 1024; off <<= 1) {
        int v = (t >= off) ? sums[t - off] : 0;
        __syncthreads();
        sums[t] += v;
        __syncthreads();
    }
    int run = (t == 0) ? 0 : sums[t - 1];
    for (int i = beg; i < end; ++i) { rowptr[i] = run; run += cnt[i]; }
    if (t == 0) rowptr[n] = sums[1023];
}

__global__ void place_kernel(const int* __restrict__ src, const int* __restrict__ dst,
                             const int* __restrict__ rowptr, int* __restrict__ cursor,
                             int* __restrict__ csr, int E) {
    int i = blockIdx.x * blockDim.x + threadIdx.x;
    if (i >= E) return;
    int d = dst[i];
    int p = atomicAdd(&cursor[d], 1);
    csr[rowptr[d] + p] = src[i];
}

// ---------------- Pre-scale: Y = diag(dinv) * X (layer-0 only; later layers fold into GEMM) ----

__global__ void prescale64_kernel(const float* __restrict__ X, const float* __restrict__ dinv,
                                  float* __restrict__ Y, int N) {
    int i = blockIdx.x * blockDim.x + threadIdx.x;  // over N*16 float4
    if (i >= N * 16) return;
    int r = i >> 4;
    float4 v = reinterpret_cast<const float4*>(X)[i];
    float d = dinv[r];
    v.x *= d; v.y *= d; v.z *= d; v.w *= d;
    reinterpret_cast<float4*>(Y)[i] = v;
}

// ---------------- Aggregation: S[i] = sum_{s in in(i)} Xs[s] + Xs[i]  (Xs pre-scaled) ----------

__global__ void agg64_kernel(const float* __restrict__ X, const int* __restrict__ rowptr,
                             const int* __restrict__ csr, float* __restrict__ S, int N) {
    int w = blockIdx.x * (blockDim.x >> 6) + (threadIdx.x >> 6);
    int lane = threadIdx.x & 63;
    if (w >= N) return;
    int beg = rowptr[w], end = rowptr[w + 1];
    float acc = X[(size_t)w * 64 + lane];  // self
    int e = beg;
    for (; e + 4 <= end; e += 4) {
        int s0 = csr[e], s1 = csr[e + 1], s2 = csr[e + 2], s3 = csr[e + 3];
        float v0 = X[(size_t)s0 * 64 + lane];
        float v1 = X[(size_t)s1 * 64 + lane];
        float v2 = X[(size_t)s2 * 64 + lane];
        float v3 = X[(size_t)s3 * 64 + lane];
        acc += (v0 + v1) + (v2 + v3);
    }
    for (; e < end; ++e) {
        int s = csr[e];
        acc += X[(size_t)s * 64 + lane];
    }
    S[(size_t)w * 64 + lane] = acc;
}

__global__ void agg128_kernel(const float* __restrict__ Xf, const int* __restrict__ rowptr,
                              const int* __restrict__ csr, float* __restrict__ Sf, int N) {
    int w = blockIdx.x * (blockDim.x >> 6) + (threadIdx.x >> 6);
    int lane = threadIdx.x & 63;
    if (w >= N) return;
    const float2* X = (const float2*)Xf;
    float2* S = (float2*)Sf;
    int beg = rowptr[w], end = rowptr[w + 1];
    float2 self = X[(size_t)w * 64 + lane];
    float ax = self.x, ay = self.y;
    int e = beg;
    for (; e + 4 <= end; e += 4) {
        int s0 = csr[e], s1 = csr[e + 1], s2 = csr[e + 2], s3 = csr[e + 3];
        float2 v0 = X[(size_t)s0 * 64 + lane];
        float2 v1 = X[(size_t)s1 * 64 + lane];
        float2 v2 = X[(size_t)s2 * 64 + lane];
        float2 v3 = X[(size_t)s3 * 64 + lane];
        ax += (v0.x + v1.x) + (v2.x + v3.x);
        ay += (v0.y + v1.y) + (v2.y + v3.y);
    }
    for (; e < end; ++e) {
        int s = csr[e];
        float2 v = X[(size_t)s * 64 + lane];
        ax += v.x; ay += v.y;
    }
    float2 r; r.x = ax; r.y = ay;
    S[(size_t)w * 64 + lane] = r;
}

// ---- GEMM: C[r] = po(r) * relu(dinv[r]*(A[r] @ W) + bias), po = dinv[r] if post else 1 ------
// BM=64, BN=128, BK=32, 256 threads, micro-tile 8 rows x 4 cols.

template <int K>
__global__ __launch_bounds__(256) void gemm_relu(const float* __restrict__ A,
                                                 const float* __restrict__ W,
                                                 const float* __restrict__ B,
                                                 const float* __restrict__ dinv, int post,
                                                 float* __restrict__ C, int M) {
    const int BK = 32;
    __shared__ float As[BK][68];   // [k][r], pad 68 keeps float4 alignment
    __shared__ float Ws[BK][128];  // [k][c]

    int t = threadIdx.x;
    int tx = t & 31, ty = t >> 5;  // tx: col-quad 0..31, ty: row-group 0..7
    int row0 = blockIdx.x * 64;

    float acc[8][4];
#pragma unroll
    for (int i = 0; i < 8; ++i)
#pragma unroll
        for (int j = 0; j < 4; ++j) acc[i][j] = 0.f;

    for (int k0 = 0; k0 < K; k0 += BK) {
        // A tile: 64 rows x 32 k = 512 float4, 2 per thread; store transposed As[k][r]
#pragma unroll
        for (int l = 0; l < 2; ++l) {
            int j = t + l * 256;
            int r = j >> 3, kq = j & 7;
            int gr = row0 + r; if (gr >= M) gr = M - 1;
            float4 v = *reinterpret_cast<const float4*>(A + (size_t)gr * K + k0 + kq * 4);
            As[kq * 4 + 0][r] = v.x;
            As[kq * 4 + 1][r] = v.y;
            As[kq * 4 + 2][r] = v.z;
            As[kq * 4 + 3][r] = v.w;
        }
        // W tile: 32 k x 128 c = 1024 float4, 4 per thread
#pragma unroll
        for (int l = 0; l < 4; ++l) {
            int j = t + l * 256;
            int k = j >> 5, c4 = j & 31;
            *reinterpret_cast<float4*>(&Ws[k][c4 * 4]) =
                *reinterpret_cast<const float4*>(W + (size_t)(k0 + k) * 128 + c4 * 4);
        }
        __syncthreads();
#pragma unroll
        for (int k = 0; k < BK; ++k) {
            float4 w0 = *reinterpret_cast<const float4*>(&Ws[k][tx * 4]);
            float4 a0 = *reinterpret_cast<const float4*>(&As[k][ty * 8]);
            float4 a1 = *reinterpret_cast<const float4*>(&As[k][ty * 8 + 4]);
            float a[8] = {a0.x, a0.y, a0.z, a0.w, a1.x, a1.y, a1.z, a1.w};
            float wv[4] = {w0.x, w0.y, w0.z, w0.w};
#pragma unroll
            for (int i = 0; i < 8; ++i)
#pragma unroll
                for (int j = 0; j < 4; ++j) acc[i][j] += a[i] * wv[j];
        }
        __syncthreads();
    }

    float4 bc = *reinterpret_cast<const float4*>(B + tx * 4);
#pragma unroll
    for (int i = 0; i < 8; ++i) {
        int r = row0 + ty * 8 + i;
        if (r < M) {
            float d = dinv[r];
            float po = post ? d : 1.0f;
            float4 v;
            v.x = fmaxf(acc[i][0] * d + bc.x, 0.f) * po;
            v.y = fmaxf(acc[i][1] * d + bc.y, 0.f) * po;
            v.z = fmaxf(acc[i][2] * d + bc.z, 0.f) * po;
            v.w = fmaxf(acc[i][3] * d + bc.w, 0.f) * po;
            *reinterpret_cast<float4*>(&C[(size_t)r * 128 + tx * 4]) = v;
        }
    }
}

// ---------------- Final FC: out[p] = relu(concat(HL[l0], HR[l1]) @ fcW + fcb) ----------------

__global__ void fc_kernel(const float* __restrict__ HL, const float* __restrict__ HR,
                          const int* __restrict__ label, const float* __restrict__ fcW,
                          const float* __restrict__ fcb, float* __restrict__ out, int P) {
    int w = blockIdx.x * (blockDim.x >> 6) + (threadIdx.x >> 6);
    int lane = threadIdx.x & 63;
    if (w >= P) return;
    int l0 = label[2 * w], l1 = label[2 * w + 1];
    float xl0 = HL[(size_t)l0 * 128 + lane];
    float xl1 = HL[(size_t)l0 * 128 + 64 + lane];
    float xr0 = HR[(size_t)l1 * 128 + lane];
    float xr1 = HR[(size_t)l1 * 128 + 64 + lane];
    float a0 = xl0 * fcW[lane * 2]             + xl1 * fcW[(64 + lane) * 2]
             + xr0 * fcW[(128 + lane) * 2]     + xr1 * fcW[(192 + lane) * 2];
    float a1 = xl0 * fcW[lane * 2 + 1]         + xl1 * fcW[(64 + lane) * 2 + 1]
             + xr0 * fcW[(128 + lane) * 2 + 1] + xr1 * fcW[(192 + lane) * 2 + 1];
#pragma unroll
    for (int o = 32; o; o >>= 1) {
        a0 += __shfl_xor(a0, o);
        a1 += __shfl_xor(a1, o);
    }
    if (lane == 0) {
        out[2 * w]     = fmaxf(a0 + fcb[0], 0.f);
        out[2 * w + 1] = fmaxf(a1 + fcb[1], 0.f);
    }
}

// ---------------- launch ----------------

extern "C" void kernel_launch(void* const* d_in, const int* in_sizes, int n_in,
                              void* d_out, int out_size, void* d_ws, size_t ws_size,
                              hipStream_t stream) {
    const float* x1   = (const float*)d_in[0];
    const int*   e1   = (const int*)d_in[1];
    const float* x2   = (const float*)d_in[2];
    const int*   e2   = (const int*)d_in[3];
    const int*   label= (const int*)d_in[4];
    const float* W0   = (const float*)d_in[5];
    const float* b0   = (const float*)d_in[6];
    const float* W1   = (const float*)d_in[7];
    const float* b1   = (const float*)d_in[8];
    const float* W2   = (const float*)d_in[9];
    const float* b2   = (const float*)d_in[10];
    const float* fcW  = (const float*)d_in[11];
    const float* fcb  = (const float*)d_in[12];
    float* out = (float*)d_out;

    const int N = in_sizes[0] / 64;
    const int E = in_sizes[1] / 2;
    const int P = in_sizes[4] / 2;

    char* ws = (char*)d_ws;
    size_t off = 0;
    auto alloc = [&](size_t bytes) -> void* {
        void* p = ws + off;
        off += (bytes + 255) & ~(size_t)255;
        return p;
    };
    int*   cnt    = (int*)alloc((size_t)N * 4);
    int*   rowptr = (int*)alloc((size_t)(N + 1) * 4);
    float* dinv   = (float*)alloc((size_t)N * 4);
    int*   csr    = (int*)alloc((size_t)E * 4);
    float* Xs     = (float*)alloc((size_t)N * 128 * 4);  // pre-scaled activations
    float* S      = (float*)alloc((size_t)N * 128 * 4);  // aggregated
    float* H3L    = (float*)alloc((size_t)N * 128 * 4);  // tower-1 output

    auto run_graph = [&](const float* x, const int* ei, float* Hout) {
        const int* src = ei;
        const int* dst = ei + E;
        hipMemsetAsync(cnt, 0, (size_t)N * 4, stream);
        hist_kernel<<<(E + 255) / 256, 256, 0, stream>>>(dst, cnt, E);
        dinv_kernel<<<(N + 255) / 256, 256, 0, stream>>>(cnt, dinv, N);
        scan_kernel<<<1, 1024, 0, stream>>>(cnt, rowptr, N);
        hipMemsetAsync(cnt, 0, (size_t)N * 4, stream);
        place_kernel<<<(E + 255) / 256, 256, 0, stream>>>(src, dst, rowptr, cnt, csr, E);
        // layer 0: pre-scale x, aggregate (64), GEMM 64->128 (pre+post dinv scaling)
        prescale64_kernel<<<(N * 16 + 255) / 256, 256, 0, stream>>>(x, dinv, Xs, N);
        agg64_kernel<<<(N + 3) / 4, 256, 0, stream>>>(Xs, rowptr, csr, S, N);
        gemm_relu<64><<<(N + 63) / 64, 256, 0, stream>>>(S, W0, b0, dinv, 1, Xs, N);
        // layer 1
        agg128_kernel<<<(N + 3) / 4, 256, 0, stream>>>(Xs, rowptr, csr, S, N);
        gemm_relu<128><<<(N + 63) / 64, 256, 0, stream>>>(S, W1, b1, dinv, 1, Xs, N);
        // layer 2 (no post-scale: plain H3)
        agg128_kernel<<<(N + 3) / 4, 256, 0, stream>>>(Xs, rowptr, csr, S, N);
        gemm_relu<128><<<(N + 63) / 64, 256, 0, stream>>>(S, W2, b2, dinv, 0, Hout, N);
    };

    run_graph(x1, e1, H3L);
    run_graph(x2, e2, Xs);  // tower-2 output reuses Xs (final gemm reads S, writes Xs)

    fc_kernel<<<(P + 3) / 4, 256, 0, stream>>>(H3L, Xs, label, fcW, fcb, out, P);
}

// Round 3
// 671.793 us; speedup vs baseline: 1.4899x; 1.2037x over previous
//
#include <hip/hip_runtime.h>
#include <math.h>

// ---------------- CSR build ----------------

__global__ void hist_kernel(const int* __restrict__ dst, int* __restrict__ cnt, int E) {
    int i = blockIdx.x * blockDim.x + threadIdx.x;
    if (i < E) atomicAdd(&cnt[dst[i]], 1);
}

// Phase A: per-block (256-elem) reduction of cnt, plus dinv computation.
__global__ __launch_bounds__(256) void block_reduce_kernel(const int* __restrict__ cnt,
                                                           float* __restrict__ dinv,
                                                           int* __restrict__ blockSums, int N) {
    int i = blockIdx.x * 256 + threadIdx.x;
    int v = 0;
    if (i < N) {
        v = cnt[i];
        dinv[i] = 1.0f / sqrtf((float)(v + 1));  // +1 self loop
    }
    int s = v;
#pragma unroll
    for (int o = 32; o; o >>= 1) s += __shfl_down(s, o);
    __shared__ int ws[4];
    if ((threadIdx.x & 63) == 0) ws[threadIdx.x >> 6] = s;
    __syncthreads();
    if (threadIdx.x == 0) blockSums[blockIdx.x] = ws[0] + ws[1] + ws[2] + ws[3];
}

// Phase B: scan the (<=1024) block sums -> exclusive offsets; write rowptr[N] = total.
__global__ __launch_bounds__(1024) void scan_sums_kernel(const int* __restrict__ blockSums,
                                                         int* __restrict__ blockOff, int nb,
                                                         int* __restrict__ rowptr, int N) {
    __shared__ int sh[1024];
    int t = threadIdx.x;
    int v = (t < nb) ? blockSums[t] : 0;
    sh[t] = v;
    __syncthreads();
    for (int o = 1; o < 1024; o <<= 1) {
        int u = (t >= o) ? sh[t - o] : 0;
        __syncthreads();
        sh[t] += u;
        __syncthreads();
    }
    if (t < nb) blockOff[t] = sh[t] - v;  // exclusive
    if (t == 1023) rowptr[N] = sh[1023];
}

// Phase C: in-block exclusive scan of cnt + block offset -> rowptr.
__global__ __launch_bounds__(256) void scan_write_kernel(const int* __restrict__ cnt,
                                                         const int* __restrict__ blockOff,
                                                         int* __restrict__ rowptr, int N) {
    __shared__ int sh[256];
    int i = blockIdx.x * 256 + threadIdx.x;
    int t = threadIdx.x;
    int v = (i < N) ? cnt[i] : 0;
    sh[t] = v;
    __syncthreads();
    for (int o = 1; o < 256; o <<= 1) {
        int u = (t >= o) ? sh[t - o] : 0;
        __syncthreads();
        sh[t] += u;
        __syncthreads();
    }
    if (i < N) rowptr[i] = blockOff[blockIdx.x] + sh[t] - v;
}

// Place: atomicSub drains cnt to zero (so no re-memset needed for the next graph).
__global__ void place_kernel(const int* __restrict__ src, const int* __restrict__ dst,
                             const int* __restrict__ rowptr, int* __restrict__ cnt,
                             int* __restrict__ csr, int E) {
    int i = blockIdx.x * blockDim.x + threadIdx.x;
    if (i >= E) return;
    int d = dst[i];
    int p = atomicSub(&cnt[d], 1);  // returns old count, 1..deg
    csr[rowptr[d] + p - 1] = src[i];
}

// ---------------- Pre-scale: Y = diag(dinv) * X (layer-0 only) ----------------

__global__ void prescale64_kernel(const float* __restrict__ X, const float* __restrict__ dinv,
                                  float* __restrict__ Y, int N) {
    int i = blockIdx.x * blockDim.x + threadIdx.x;  // over N*16 float4
    if (i >= N * 16) return;
    int r = i >> 4;
    float4 v = reinterpret_cast<const float4*>(X)[i];
    float d = dinv[r];
    v.x *= d; v.y *= d; v.z *= d; v.w *= d;
    reinterpret_cast<float4*>(Y)[i] = v;
}

// ---------------- Aggregation: S[i] = sum_{s in in(i)} Xs[s] + Xs[i]  (Xs pre-scaled) --------

__global__ void agg64_kernel(const float* __restrict__ X, const int* __restrict__ rowptr,
                             const int* __restrict__ csr, float* __restrict__ S, int N) {
    int w = blockIdx.x * (blockDim.x >> 6) + (threadIdx.x >> 6);
    int lane = threadIdx.x & 63;
    if (w >= N) return;
    int beg = rowptr[w], end = rowptr[w + 1];
    float acc = X[(size_t)w * 64 + lane];  // self
    int e = beg;
    for (; e + 8 <= end; e += 8) {
        int s0 = csr[e], s1 = csr[e + 1], s2 = csr[e + 2], s3 = csr[e + 3];
        int s4 = csr[e + 4], s5 = csr[e + 5], s6 = csr[e + 6], s7 = csr[e + 7];
        float v0 = X[(size_t)s0 * 64 + lane];
        float v1 = X[(size_t)s1 * 64 + lane];
        float v2 = X[(size_t)s2 * 64 + lane];
        float v3 = X[(size_t)s3 * 64 + lane];
        float v4 = X[(size_t)s4 * 64 + lane];
        float v5 = X[(size_t)s5 * 64 + lane];
        float v6 = X[(size_t)s6 * 64 + lane];
        float v7 = X[(size_t)s7 * 64 + lane];
        acc += ((v0 + v1) + (v2 + v3)) + ((v4 + v5) + (v6 + v7));
    }
    for (; e < end; ++e) {
        acc += X[(size_t)csr[e] * 64 + lane];
    }
    S[(size_t)w * 64 + lane] = acc;
}

__global__ void agg128_kernel(const float* __restrict__ Xf, const int* __restrict__ rowptr,
                              const int* __restrict__ csr, float* __restrict__ Sf, int N) {
    int w = blockIdx.x * (blockDim.x >> 6) + (threadIdx.x >> 6);
    int lane = threadIdx.x & 63;
    if (w >= N) return;
    const float2* X = (const float2*)Xf;
    float2* S = (float2*)Sf;
    int beg = rowptr[w], end = rowptr[w + 1];
    float2 self = X[(size_t)w * 64 + lane];
    float ax = self.x, ay = self.y;
    int e = beg;
    for (; e + 8 <= end; e += 8) {
        int s0 = csr[e], s1 = csr[e + 1], s2 = csr[e + 2], s3 = csr[e + 3];
        int s4 = csr[e + 4], s5 = csr[e + 5], s6 = csr[e + 6], s7 = csr[e + 7];
        float2 v0 = X[(size_t)s0 * 64 + lane];
        float2 v1 = X[(size_t)s1 * 64 + lane];
        float2 v2 = X[(size_t)s2 * 64 + lane];
        float2 v3 = X[(size_t)s3 * 64 + lane];
        float2 v4 = X[(size_t)s4 * 64 + lane];
        float2 v5 = X[(size_t)s5 * 64 + lane];
        float2 v6 = X[(size_t)s6 * 64 + lane];
        float2 v7 = X[(size_t)s7 * 64 + lane];
        ax += ((v0.x + v1.x) + (v2.x + v3.x)) + ((v4.x + v5.x) + (v6.x + v7.x));
        ay += ((v0.y + v1.y) + (v2.y + v3.y)) + ((v4.y + v5.y) + (v6.y + v7.y));
    }
    for (; e < end; ++e) {
        float2 v = X[(size_t)csr[e] * 64 + lane];
        ax += v.x; ay += v.y;
    }
    float2 r; r.x = ax; r.y = ay;
    S[(size_t)w * 64 + lane] = r;
}

// ---- GEMM: C[r] = po(r) * relu(dinv[r]*(A[r] @ W) + bias), po = dinv[r] if post else 1 ------

template <int K>
__global__ __launch_bounds__(256) void gemm_relu(const float* __restrict__ A,
                                                 const float* __restrict__ W,
                                                 const float* __restrict__ B,
                                                 const float* __restrict__ dinv, int post,
                                                 float* __restrict__ C, int M) {
    const int BK = 32;
    __shared__ float As[BK][68];
    __shared__ float Ws[BK][128];

    int t = threadIdx.x;
    int tx = t & 31, ty = t >> 5;
    int row0 = blockIdx.x * 64;

    float acc[8][4];
#pragma unroll
    for (int i = 0; i < 8; ++i)
#pragma unroll
        for (int j = 0; j < 4; ++j) acc[i][j] = 0.f;

    for (int k0 = 0; k0 < K; k0 += BK) {
#pragma unroll
        for (int l = 0; l < 2; ++l) {
            int j = t + l * 256;
            int r = j >> 3, kq = j & 7;
            int gr = row0 + r; if (gr >= M) gr = M - 1;
            float4 v = *reinterpret_cast<const float4*>(A + (size_t)gr * K + k0 + kq * 4);
            As[kq * 4 + 0][r] = v.x;
            As[kq * 4 + 1][r] = v.y;
            As[kq * 4 + 2][r] = v.z;
            As[kq * 4 + 3][r] = v.w;
        }
#pragma unroll
        for (int l = 0; l < 4; ++l) {
            int j = t + l * 256;
            int k = j >> 5, c4 = j & 31;
            *reinterpret_cast<float4*>(&Ws[k][c4 * 4]) =
                *reinterpret_cast<const float4*>(W + (size_t)(k0 + k) * 128 + c4 * 4);
        }
        __syncthreads();
#pragma unroll
        for (int k = 0; k < BK; ++k) {
            float4 w0 = *reinterpret_cast<const float4*>(&Ws[k][tx * 4]);
            float4 a0 = *reinterpret_cast<const float4*>(&As[k][ty * 8]);
            float4 a1 = *reinterpret_cast<const float4*>(&As[k][ty * 8 + 4]);
            float a[8] = {a0.x, a0.y, a0.z, a0.w, a1.x, a1.y, a1.z, a1.w};
            float wv[4] = {w0.x, w0.y, w0.z, w0.w};
#pragma unroll
            for (int i = 0; i < 8; ++i)
#pragma unroll
                for (int j = 0; j < 4; ++j) acc[i][j] += a[i] * wv[j];
        }
        __syncthreads();
    }

    float4 bc = *reinterpret_cast<const float4*>(B + tx * 4);
#pragma unroll
    for (int i = 0; i < 8; ++i) {
        int r = row0 + ty * 8 + i;
        if (r < M) {
            float d = dinv[r];
            float po = post ? d : 1.0f;
            float4 v;
            v.x = fmaxf(acc[i][0] * d + bc.x, 0.f) * po;
            v.y = fmaxf(acc[i][1] * d + bc.y, 0.f) * po;
            v.z = fmaxf(acc[i][2] * d + bc.z, 0.f) * po;
            v.w = fmaxf(acc[i][3] * d + bc.w, 0.f) * po;
            *reinterpret_cast<float4*>(&C[(size_t)r * 128 + tx * 4]) = v;
        }
    }
}

// ---------------- Final FC ----------------

__global__ void fc_kernel(const float* __restrict__ HL, const float* __restrict__ HR,
                          const int* __restrict__ label, const float* __restrict__ fcW,
                          const float* __restrict__ fcb, float* __restrict__ out, int P) {
    int w = blockIdx.x * (blockDim.x >> 6) + (threadIdx.x >> 6);
    int lane = threadIdx.x & 63;
    if (w >= P) return;
    int l0 = label[2 * w], l1 = label[2 * w + 1];
    float xl0 = HL[(size_t)l0 * 128 + lane];
    float xl1 = HL[(size_t)l0 * 128 + 64 + lane];
    float xr0 = HR[(size_t)l1 * 128 + lane];
    float xr1 = HR[(size_t)l1 * 128 + 64 + lane];
    float a0 = xl0 * fcW[lane * 2]             + xl1 * fcW[(64 + lane) * 2]
             + xr0 * fcW[(128 + lane) * 2]     + xr1 * fcW[(192 + lane) * 2];
    float a1 = xl0 * fcW[lane * 2 + 1]         + xl1 * fcW[(64 + lane) * 2 + 1]
             + xr0 * fcW[(128 + lane) * 2 + 1] + xr1 * fcW[(192 + lane) * 2 + 1];
#pragma unroll
    for (int o = 32; o; o >>= 1) {
        a0 += __shfl_xor(a0, o);
        a1 += __shfl_xor(a1, o);
    }
    if (lane == 0) {
        out[2 * w]     = fmaxf(a0 + fcb[0], 0.f);
        out[2 * w + 1] = fmaxf(a1 + fcb[1], 0.f);
    }
}

// ---------------- launch ----------------

extern "C" void kernel_launch(void* const* d_in, const int* in_sizes, int n_in,
                              void* d_out, int out_size, void* d_ws, size_t ws_size,
                              hipStream_t stream) {
    const float* x1   = (const float*)d_in[0];
    const int*   e1   = (const int*)d_in[1];
    const float* x2   = (const float*)d_in[2];
    const int*   e2   = (const int*)d_in[3];
    const int*   label= (const int*)d_in[4];
    const float* W0   = (const float*)d_in[5];
    const float* b0   = (const float*)d_in[6];
    const float* W1   = (const float*)d_in[7];
    const float* b1   = (const float*)d_in[8];
    const float* W2   = (const float*)d_in[9];
    const float* b2   = (const float*)d_in[10];
    const float* fcW  = (const float*)d_in[11];
    const float* fcb  = (const float*)d_in[12];
    float* out = (float*)d_out;

    const int N = in_sizes[0] / 64;
    const int E = in_sizes[1] / 2;
    const int P = in_sizes[4] / 2;
    const int NB = (N + 255) / 256;  // scan blocks (196 for N=50000)

    char* ws = (char*)d_ws;
    size_t off = 0;
    auto alloc = [&](size_t bytes) -> void* {
        void* p = ws + off;
        off += (bytes + 255) & ~(size_t)255;
        return p;
    };
    int*   cnt      = (int*)alloc((size_t)N * 4);
    int*   rowptr   = (int*)alloc((size_t)(N + 1) * 4);
    float* dinv     = (float*)alloc((size_t)N * 4);
    int*   csr      = (int*)alloc((size_t)E * 4);
    int*   blockSums= (int*)alloc((size_t)NB * 4);
    int*   blockOff = (int*)alloc((size_t)NB * 4);
    float* Xs       = (float*)alloc((size_t)N * 128 * 4);
    float* S        = (float*)alloc((size_t)N * 128 * 4);
    float* H3L      = (float*)alloc((size_t)N * 128 * 4);

    auto run_graph = [&](const float* x, const int* ei, float* Hout, bool first) {
        const int* src = ei;
        const int* dst = ei + E;
        // cnt is all-zero after the previous graph's place_kernel (atomicSub drains it);
        // only the first graph needs a memset (d_ws is poisoned before timing).
        if (first) hipMemsetAsync(cnt, 0, (size_t)N * 4, stream);
        hist_kernel<<<(E + 255) / 256, 256, 0, stream>>>(dst, cnt, E);
        block_reduce_kernel<<<NB, 256, 0, stream>>>(cnt, dinv, blockSums, N);
        scan_sums_kernel<<<1, 1024, 0, stream>>>(blockSums, blockOff, NB, rowptr, N);
        scan_write_kernel<<<NB, 256, 0, stream>>>(cnt, blockOff, rowptr, N);
        place_kernel<<<(E + 255) / 256, 256, 0, stream>>>(src, dst, rowptr, cnt, csr, E);
        // layer 0
        prescale64_kernel<<<(N * 16 + 255) / 256, 256, 0, stream>>>(x, dinv, Xs, N);
        agg64_kernel<<<(N + 3) / 4, 256, 0, stream>>>(Xs, rowptr, csr, S, N);
        gemm_relu<64><<<(N + 63) / 64, 256, 0, stream>>>(S, W0, b0, dinv, 1, Xs, N);
        // layer 1
        agg128_kernel<<<(N + 3) / 4, 256, 0, stream>>>(Xs, rowptr, csr, S, N);
        gemm_relu<128><<<(N + 63) / 64, 256, 0, stream>>>(S, W1, b1, dinv, 1, Xs, N);
        // layer 2 (no post-scale)
        agg128_kernel<<<(N + 3) / 4, 256, 0, stream>>>(Xs, rowptr, csr, S, N);
        gemm_relu<128><<<(N + 63) / 64, 256, 0, stream>>>(S, W2, b2, dinv, 0, Hout, N);
    };

    run_graph(x1, e1, H3L, true);
    run_graph(x2, e2, Xs, false);  // tower-2 output reuses Xs

    fc_kernel<<<(P + 3) / 4, 256, 0, stream>>>(H3L, Xs, label, fcW, fcb, out, P);
}

// Round 4
// 611.237 us; speedup vs baseline: 1.6375x; 1.0991x over previous
//
#include <hip/hip_runtime.h>
#include <math.h>

// Two input graphs are processed as ONE disjoint-union graph:
// nodes [0,N) = graph1, [N,2N) = graph2; 2E edges. Shared GCN weights make
// every per-layer kernel run once over 2N rows.

// ---------------- CSR build (union) ----------------

__global__ void histU_kernel(const int* __restrict__ d1, const int* __restrict__ d2,
                             int* __restrict__ cnt, int E, int N) {
    int i = blockIdx.x * blockDim.x + threadIdx.x;
    if (i < E) atomicAdd(&cnt[d1[i]], 1);
    else if (i < 2 * E) atomicAdd(&cnt[N + d2[i - E]], 1);
}

// Phase A: per-block (256-elem) reduction of cnt, plus dinv computation.
__global__ __launch_bounds__(256) void block_reduce_kernel(const int* __restrict__ cnt,
                                                           float* __restrict__ dinv,
                                                           int* __restrict__ blockSums, int NN) {
    int i = blockIdx.x * 256 + threadIdx.x;
    int v = 0;
    if (i < NN) {
        v = cnt[i];
        dinv[i] = 1.0f / sqrtf((float)(v + 1));  // +1 self loop
    }
    int s = v;
#pragma unroll
    for (int o = 32; o; o >>= 1) s += __shfl_down(s, o);
    __shared__ int ws[4];
    if ((threadIdx.x & 63) == 0) ws[threadIdx.x >> 6] = s;
    __syncthreads();
    if (threadIdx.x == 0) blockSums[blockIdx.x] = ws[0] + ws[1] + ws[2] + ws[3];
}

// Phase B: scan the (<=1024) block sums -> exclusive offsets.
__global__ __launch_bounds__(1024) void scan_sums_kernel(const int* __restrict__ blockSums,
                                                         int* __restrict__ blockOff, int nb,
                                                         int* __restrict__ rowptr, int NN) {
    __shared__ int sh[1024];
    int t = threadIdx.x;
    int v = (t < nb) ? blockSums[t] : 0;
    sh[t] = v;
    __syncthreads();
    for (int o = 1; o < 1024; o <<= 1) {
        int u = (t >= o) ? sh[t - o] : 0;
        __syncthreads();
        sh[t] += u;
        __syncthreads();
    }
    if (t < nb) blockOff[t] = sh[t] - v;  // exclusive
    if (t == 1023) rowptr[NN] = sh[1023];
}

// Phase C: in-block exclusive scan of cnt + block offset -> rowptr.
__global__ __launch_bounds__(256) void scan_write_kernel(const int* __restrict__ cnt,
                                                         const int* __restrict__ blockOff,
                                                         int* __restrict__ rowptr, int NN) {
    __shared__ int sh[256];
    int i = blockIdx.x * 256 + threadIdx.x;
    int t = threadIdx.x;
    int v = (i < NN) ? cnt[i] : 0;
    sh[t] = v;
    __syncthreads();
    for (int o = 1; o < 256; o <<= 1) {
        int u = (t >= o) ? sh[t - o] : 0;
        __syncthreads();
        sh[t] += u;
        __syncthreads();
    }
    if (i < NN) rowptr[i] = blockOff[blockIdx.x] + sh[t] - v;
}

// Place: atomicSub drains cnt back to zero.
__global__ void placeU_kernel(const int* __restrict__ s1, const int* __restrict__ d1,
                              const int* __restrict__ s2, const int* __restrict__ d2,
                              const int* __restrict__ rowptr, int* __restrict__ cnt,
                              int* __restrict__ csr, int E, int N) {
    int i = blockIdx.x * blockDim.x + threadIdx.x;
    int s, d;
    if (i < E)          { s = s1[i];         d = d1[i]; }
    else if (i < 2 * E) { s = s2[i - E] + N; d = d2[i - E] + N; }
    else return;
    int p = atomicSub(&cnt[d], 1);  // old count, 1..deg
    csr[rowptr[d] + p - 1] = s;
}

// ------- Layer-0 aggregation from raw inputs, dinv folded in (no prescale pass) -------
// S[i] = sum_{s in in(i)} dinv[s]*x[s] + dinv[i]*x[i]

__global__ void agg64U_kernel(const float* __restrict__ x1, const float* __restrict__ x2,
                              const int* __restrict__ rowptr, const int* __restrict__ csr,
                              const float* __restrict__ dinv, float* __restrict__ S,
                              int NN, int N) {
    int w = blockIdx.x * (blockDim.x >> 6) + (threadIdx.x >> 6);
    int lane = threadIdx.x & 63;
    if (w >= NN) return;
    int beg = rowptr[w], end = rowptr[w + 1];
    const float* selfrow = (w < N) ? (x1 + (size_t)w * 64) : (x2 + (size_t)(w - N) * 64);
    float acc = dinv[w] * selfrow[lane];
    int e = beg;
    for (; e + 8 <= end; e += 8) {
        int s0 = csr[e], s1 = csr[e + 1], s2 = csr[e + 2], s3 = csr[e + 3];
        int s4 = csr[e + 4], s5 = csr[e + 5], s6 = csr[e + 6], s7 = csr[e + 7];
        const float* r0 = (s0 < N) ? (x1 + (size_t)s0 * 64) : (x2 + (size_t)(s0 - N) * 64);
        const float* r1 = (s1 < N) ? (x1 + (size_t)s1 * 64) : (x2 + (size_t)(s1 - N) * 64);
        const float* r2 = (s2 < N) ? (x1 + (size_t)s2 * 64) : (x2 + (size_t)(s2 - N) * 64);
        const float* r3 = (s3 < N) ? (x1 + (size_t)s3 * 64) : (x2 + (size_t)(s3 - N) * 64);
        const float* r4 = (s4 < N) ? (x1 + (size_t)s4 * 64) : (x2 + (size_t)(s4 - N) * 64);
        const float* r5 = (s5 < N) ? (x1 + (size_t)s5 * 64) : (x2 + (size_t)(s5 - N) * 64);
        const float* r6 = (s6 < N) ? (x1 + (size_t)s6 * 64) : (x2 + (size_t)(s6 - N) * 64);
        const float* r7 = (s7 < N) ? (x1 + (size_t)s7 * 64) : (x2 + (size_t)(s7 - N) * 64);
        float v0 = dinv[s0] * r0[lane];
        float v1 = dinv[s1] * r1[lane];
        float v2 = dinv[s2] * r2[lane];
        float v3 = dinv[s3] * r3[lane];
        float v4 = dinv[s4] * r4[lane];
        float v5 = dinv[s5] * r5[lane];
        float v6 = dinv[s6] * r6[lane];
        float v7 = dinv[s7] * r7[lane];
        acc += ((v0 + v1) + (v2 + v3)) + ((v4 + v5) + (v6 + v7));
    }
    for (; e < end; ++e) {
        int s = csr[e];
        const float* r = (s < N) ? (x1 + (size_t)s * 64) : (x2 + (size_t)(s - N) * 64);
        acc += dinv[s] * r[lane];
    }
    S[(size_t)w * 64 + lane] = acc;
}

// ------- Layers 1-2 aggregation: inputs already pre-scaled by GEMM epilogue -------

__global__ void agg128_kernel(const float* __restrict__ Xf, const int* __restrict__ rowptr,
                              const int* __restrict__ csr, float* __restrict__ Sf, int NN) {
    int w = blockIdx.x * (blockDim.x >> 6) + (threadIdx.x >> 6);
    int lane = threadIdx.x & 63;
    if (w >= NN) return;
    const float2* X = (const float2*)Xf;
    float2* S = (float2*)Sf;
    int beg = rowptr[w], end = rowptr[w + 1];
    float2 self = X[(size_t)w * 64 + lane];
    float ax = self.x, ay = self.y;
    int e = beg;
    for (; e + 8 <= end; e += 8) {
        int s0 = csr[e], s1 = csr[e + 1], s2 = csr[e + 2], s3 = csr[e + 3];
        int s4 = csr[e + 4], s5 = csr[e + 5], s6 = csr[e + 6], s7 = csr[e + 7];
        float2 v0 = X[(size_t)s0 * 64 + lane];
        float2 v1 = X[(size_t)s1 * 64 + lane];
        float2 v2 = X[(size_t)s2 * 64 + lane];
        float2 v3 = X[(size_t)s3 * 64 + lane];
        float2 v4 = X[(size_t)s4 * 64 + lane];
        float2 v5 = X[(size_t)s5 * 64 + lane];
        float2 v6 = X[(size_t)s6 * 64 + lane];
        float2 v7 = X[(size_t)s7 * 64 + lane];
        ax += ((v0.x + v1.x) + (v2.x + v3.x)) + ((v4.x + v5.x) + (v6.x + v7.x));
        ay += ((v0.y + v1.y) + (v2.y + v3.y)) + ((v4.y + v5.y) + (v6.y + v7.y));
    }
    for (; e < end; ++e) {
        float2 v = X[(size_t)csr[e] * 64 + lane];
        ax += v.x; ay += v.y;
    }
    float2 r; r.x = ax; r.y = ay;
    S[(size_t)w * 64 + lane] = r;
}

// ---- GEMM: C[r] = po(r) * relu(dinv[r]*(A[r] @ W) + bias), po = dinv[r] if post else 1 ------

template <int K>
__global__ __launch_bounds__(256) void gemm_relu(const float* __restrict__ A,
                                                 const float* __restrict__ W,
                                                 const float* __restrict__ B,
                                                 const float* __restrict__ dinv, int post,
                                                 float* __restrict__ C, int M) {
    const int BK = 32;
    __shared__ float As[BK][68];
    __shared__ float Ws[BK][128];

    int t = threadIdx.x;
    int tx = t & 31, ty = t >> 5;
    int row0 = blockIdx.x * 64;

    float acc[8][4];
#pragma unroll
    for (int i = 0; i < 8; ++i)
#pragma unroll
        for (int j = 0; j < 4; ++j) acc[i][j] = 0.f;

    for (int k0 = 0; k0 < K; k0 += BK) {
#pragma unroll
        for (int l = 0; l < 2; ++l) {
            int j = t + l * 256;
            int r = j >> 3, kq = j & 7;
            int gr = row0 + r; if (gr >= M) gr = M - 1;
            float4 v = *reinterpret_cast<const float4*>(A + (size_t)gr * K + k0 + kq * 4);
            As[kq * 4 + 0][r] = v.x;
            As[kq * 4 + 1][r] = v.y;
            As[kq * 4 + 2][r] = v.z;
            As[kq * 4 + 3][r] = v.w;
        }
#pragma unroll
        for (int l = 0; l < 4; ++l) {
            int j = t + l * 256;
            int k = j >> 5, c4 = j & 31;
            *reinterpret_cast<float4*>(&Ws[k][c4 * 4]) =
                *reinterpret_cast<const float4*>(W + (size_t)(k0 + k) * 128 + c4 * 4);
        }
        __syncthreads();
#pragma unroll
        for (int k = 0; k < BK; ++k) {
            float4 w0 = *reinterpret_cast<const float4*>(&Ws[k][tx * 4]);
            float4 a0 = *reinterpret_cast<const float4*>(&As[k][ty * 8]);
            float4 a1 = *reinterpret_cast<const float4*>(&As[k][ty * 8 + 4]);
            float a[8] = {a0.x, a0.y, a0.z, a0.w, a1.x, a1.y, a1.z, a1.w};
            float wv[4] = {w0.x, w0.y, w0.z, w0.w};
#pragma unroll
            for (int i = 0; i < 8; ++i)
#pragma unroll
                for (int j = 0; j < 4; ++j) acc[i][j] += a[i] * wv[j];
        }
        __syncthreads();
    }

    float4 bc = *reinterpret_cast<const float4*>(B + tx * 4);
#pragma unroll
    for (int i = 0; i < 8; ++i) {
        int r = row0 + ty * 8 + i;
        if (r < M) {
            float d = dinv[r];
            float po = post ? d : 1.0f;
            float4 v;
            v.x = fmaxf(acc[i][0] * d + bc.x, 0.f) * po;
            v.y = fmaxf(acc[i][1] * d + bc.y, 0.f) * po;
            v.z = fmaxf(acc[i][2] * d + bc.z, 0.f) * po;
            v.w = fmaxf(acc[i][3] * d + bc.w, 0.f) * po;
            *reinterpret_cast<float4*>(&C[(size_t)r * 128 + tx * 4]) = v;
        }
    }
}

// ---------------- Final FC ----------------

__global__ void fc_kernel(const float* __restrict__ H3, const int* __restrict__ label,
                          const float* __restrict__ fcW, const float* __restrict__ fcb,
                          float* __restrict__ out, int P, int N) {
    int w = blockIdx.x * (blockDim.x >> 6) + (threadIdx.x >> 6);
    int lane = threadIdx.x & 63;
    if (w >= P) return;
    int l0 = label[2 * w], l1 = label[2 * w + 1] + N;
    float xl0 = H3[(size_t)l0 * 128 + lane];
    float xl1 = H3[(size_t)l0 * 128 + 64 + lane];
    float xr0 = H3[(size_t)l1 * 128 + lane];
    float xr1 = H3[(size_t)l1 * 128 + 64 + lane];
    float a0 = xl0 * fcW[lane * 2]             + xl1 * fcW[(64 + lane) * 2]
             + xr0 * fcW[(128 + lane) * 2]     + xr1 * fcW[(192 + lane) * 2];
    float a1 = xl0 * fcW[lane * 2 + 1]         + xl1 * fcW[(64 + lane) * 2 + 1]
             + xr0 * fcW[(128 + lane) * 2 + 1] + xr1 * fcW[(192 + lane) * 2 + 1];
#pragma unroll
    for (int o = 32; o; o >>= 1) {
        a0 += __shfl_xor(a0, o);
        a1 += __shfl_xor(a1, o);
    }
    if (lane == 0) {
        out[2 * w]     = fmaxf(a0 + fcb[0], 0.f);
        out[2 * w + 1] = fmaxf(a1 + fcb[1], 0.f);
    }
}

// ---------------- launch ----------------

extern "C" void kernel_launch(void* const* d_in, const int* in_sizes, int n_in,
                              void* d_out, int out_size, void* d_ws, size_t ws_size,
                              hipStream_t stream) {
    const float* x1   = (const float*)d_in[0];
    const int*   e1   = (const int*)d_in[1];
    const float* x2   = (const float*)d_in[2];
    const int*   e2   = (const int*)d_in[3];
    const int*   label= (const int*)d_in[4];
    const float* W0   = (const float*)d_in[5];
    const float* b0   = (const float*)d_in[6];
    const float* W1   = (const float*)d_in[7];
    const float* b1   = (const float*)d_in[8];
    const float* W2   = (const float*)d_in[9];
    const float* b2   = (const float*)d_in[10];
    const float* fcW  = (const float*)d_in[11];
    const float* fcb  = (const float*)d_in[12];
    float* out = (float*)d_out;

    const int N = in_sizes[0] / 64;
    const int E = in_sizes[1] / 2;
    const int P = in_sizes[4] / 2;
    const int NN = 2 * N;            // union graph nodes
    const int NB = (NN + 255) / 256; // scan blocks (391 for N=50000)

    char* ws = (char*)d_ws;
    size_t off = 0;
    auto alloc = [&](size_t bytes) -> void* {
        void* p = ws + off;
        off += (bytes + 255) & ~(size_t)255;
        return p;
    };
    int*   cnt      = (int*)alloc((size_t)NN * 4);
    int*   rowptr   = (int*)alloc((size_t)(NN + 1) * 4);
    float* dinv     = (float*)alloc((size_t)NN * 4);
    int*   csr      = (int*)alloc((size_t)2 * E * 4);
    int*   blockSums= (int*)alloc((size_t)NB * 4);
    int*   blockOff = (int*)alloc((size_t)NB * 4);
    float* S        = (float*)alloc((size_t)NN * 128 * 4);  // aggregated
    float* Xs       = (float*)alloc((size_t)NN * 128 * 4);  // layer outputs (pre-scaled), then H3

    // CSR build (once, union graph)
    hipMemsetAsync(cnt, 0, (size_t)NN * 4, stream);
    histU_kernel<<<(2 * E + 255) / 256, 256, 0, stream>>>(e1 + E, e2 + E, cnt, E, N);
    block_reduce_kernel<<<NB, 256, 0, stream>>>(cnt, dinv, blockSums, NN);
    scan_sums_kernel<<<1, 1024, 0, stream>>>(blockSums, blockOff, NB, rowptr, NN);
    scan_write_kernel<<<NB, 256, 0, stream>>>(cnt, blockOff, rowptr, NN);
    placeU_kernel<<<(2 * E + 255) / 256, 256, 0, stream>>>(e1, e1 + E, e2, e2 + E,
                                                           rowptr, cnt, csr, E, N);
    // layer 0: aggregate raw x (dinv folded in), GEMM 64->128 (pre+post dinv scaling)
    agg64U_kernel<<<(NN + 3) / 4, 256, 0, stream>>>(x1, x2, rowptr, csr, dinv, S, NN, N);
    gemm_relu<64><<<(NN + 63) / 64, 256, 0, stream>>>(S, W0, b0, dinv, 1, Xs, NN);
    // layer 1
    agg128_kernel<<<(NN + 3) / 4, 256, 0, stream>>>(Xs, rowptr, csr, S, NN);
    gemm_relu<128><<<(NN + 63) / 64, 256, 0, stream>>>(S, W1, b1, dinv, 1, Xs, NN);
    // layer 2 (no post-scale): H3 lands in Xs (gemm reads only S)
    agg128_kernel<<<(NN + 3) / 4, 256, 0, stream>>>(Xs, rowptr, csr, S, NN);
    gemm_relu<128><<<(NN + 63) / 64, 256, 0, stream>>>(S, W2, b2, dinv, 0, Xs, NN);

    fc_kernel<<<(P + 3) / 4, 256, 0, stream>>>(Xs, label, fcW, fcb, out, P, N);
}

// Round 5
// 584.602 us; speedup vs baseline: 1.7122x; 1.0456x over previous
//
#include <hip/hip_runtime.h>
#include <math.h>

typedef __attribute__((ext_vector_type(8))) short bf16x8;
typedef __attribute__((ext_vector_type(4))) float f32x4;

__device__ inline unsigned short f2bf(float f) {
    unsigned int u = __float_as_uint(f);
    unsigned int r = u + 0x7fffu + ((u >> 16) & 1u);
    return (unsigned short)(r >> 16);
}
__device__ inline float bf2f(unsigned short b) {
    return __uint_as_float(((unsigned int)b) << 16);
}

// ---------------- CSR build (union graph: nodes [0,N)=g1, [N,2N)=g2) ----------------

__global__ void histU_kernel(const int* __restrict__ d1, const int* __restrict__ d2,
                             int* __restrict__ cnt, int E, int N) {
    int i = blockIdx.x * blockDim.x + threadIdx.x;
    if (i < E) atomicAdd(&cnt[d1[i]], 1);
    else if (i < 2 * E) atomicAdd(&cnt[N + d2[i - E]], 1);
}

__global__ __launch_bounds__(256) void block_reduce_kernel(const int* __restrict__ cnt,
                                                           float* __restrict__ dinv,
                                                           int* __restrict__ blockSums, int NN) {
    int i = blockIdx.x * 256 + threadIdx.x;
    int v = 0;
    if (i < NN) {
        v = cnt[i];
        dinv[i] = 1.0f / sqrtf((float)(v + 1));  // +1 self loop
    }
    int s = v;
#pragma unroll
    for (int o = 32; o; o >>= 1) s += __shfl_down(s, o);
    __shared__ int ws[4];
    if ((threadIdx.x & 63) == 0) ws[threadIdx.x >> 6] = s;
    __syncthreads();
    if (threadIdx.x == 0) blockSums[blockIdx.x] = ws[0] + ws[1] + ws[2] + ws[3];
}

__global__ __launch_bounds__(1024) void scan_sums_kernel(const int* __restrict__ blockSums,
                                                         int* __restrict__ blockOff, int nb,
                                                         int* __restrict__ rowptr, int NN) {
    __shared__ int sh[1024];
    int t = threadIdx.x;
    int v = (t < nb) ? blockSums[t] : 0;
    sh[t] = v;
    __syncthreads();
    for (int o = 1; o < 1024; o <<= 1) {
        int u = (t >= o) ? sh[t - o] : 0;
        __syncthreads();
        sh[t] += u;
        __syncthreads();
    }
    if (t < nb) blockOff[t] = sh[t] - v;
    if (t == 1023) rowptr[NN] = sh[1023];
}

__global__ __launch_bounds__(256) void scan_write_kernel(const int* __restrict__ cnt,
                                                         const int* __restrict__ blockOff,
                                                         int* __restrict__ rowptr, int NN) {
    __shared__ int sh[256];
    int i = blockIdx.x * 256 + threadIdx.x;
    int t = threadIdx.x;
    int v = (i < NN) ? cnt[i] : 0;
    sh[t] = v;
    __syncthreads();
    for (int o = 1; o < 256; o <<= 1) {
        int u = (t >= o) ? sh[t - o] : 0;
        __syncthreads();
        sh[t] += u;
        __syncthreads();
    }
    if (i < NN) rowptr[i] = blockOff[blockIdx.x] + sh[t] - v;
}

__global__ void placeU_kernel(const int* __restrict__ s1, const int* __restrict__ d1,
                              const int* __restrict__ s2, const int* __restrict__ d2,
                              const int* __restrict__ rowptr, int* __restrict__ cnt,
                              int* __restrict__ csr, int E, int N) {
    int i = blockIdx.x * blockDim.x + threadIdx.x;
    int s, d;
    if (i < E)          { s = s1[i];         d = d1[i]; }
    else if (i < 2 * E) { s = s2[i - E] + N; d = d2[i - E] + N; }
    else return;
    int p = atomicSub(&cnt[d], 1);  // old count, 1..deg; drains cnt to 0
    csr[rowptr[d] + p - 1] = s;
}

// ---------------- Weight prep: W[K][128] f32 -> WhT/WlT [128][K] bf16 ----------------

__global__ void prep_weights(const float* __restrict__ W0, const float* __restrict__ W1,
                             const float* __restrict__ W2,
                             unsigned short* __restrict__ W0h, unsigned short* __restrict__ W0l,
                             unsigned short* __restrict__ W1h, unsigned short* __restrict__ W1l,
                             unsigned short* __restrict__ W2h, unsigned short* __restrict__ W2l) {
    const float* W; unsigned short *Wh, *Wl; int K;
    if (blockIdx.x == 0)      { W = W0; Wh = W0h; Wl = W0l; K = 64; }
    else if (blockIdx.x == 1) { W = W1; Wh = W1h; Wl = W1l; K = 128; }
    else                      { W = W2; Wh = W2h; Wl = W2l; K = 128; }
    for (int i = threadIdx.x; i < K * 128; i += 256) {
        int k = i >> 7, c = i & 127;
        float v = W[i];
        unsigned short h = f2bf(v);
        unsigned short l = f2bf(v - bf2f(h));
        Wh[c * K + k] = h;
        Wl[c * K + k] = l;
    }
}

// ------- Layer-0 aggregation from raw inputs, dinv folded; outputs split bf16 -------

__global__ void agg64U_kernel(const float* __restrict__ x1, const float* __restrict__ x2,
                              const int* __restrict__ rowptr, const int* __restrict__ csr,
                              const float* __restrict__ dinv,
                              unsigned short* __restrict__ Shi, unsigned short* __restrict__ Slo,
                              int NN, int N) {
    int w = blockIdx.x * (blockDim.x >> 6) + (threadIdx.x >> 6);
    int lane = threadIdx.x & 63;
    if (w >= NN) return;
    int beg = rowptr[w], end = rowptr[w + 1];
    const float* selfrow = (w < N) ? (x1 + (size_t)w * 64) : (x2 + (size_t)(w - N) * 64);
    float acc = dinv[w] * selfrow[lane];
    int e = beg;
    int full_end = beg + ((end - beg) & ~7);
    for (; e < full_end; e += 8) {
        int s0 = csr[e], s1 = csr[e + 1], s2 = csr[e + 2], s3 = csr[e + 3];
        int s4 = csr[e + 4], s5 = csr[e + 5], s6 = csr[e + 6], s7 = csr[e + 7];
        const float* r0 = (s0 < N) ? (x1 + (size_t)s0 * 64) : (x2 + (size_t)(s0 - N) * 64);
        const float* r1 = (s1 < N) ? (x1 + (size_t)s1 * 64) : (x2 + (size_t)(s1 - N) * 64);
        const float* r2 = (s2 < N) ? (x1 + (size_t)s2 * 64) : (x2 + (size_t)(s2 - N) * 64);
        const float* r3 = (s3 < N) ? (x1 + (size_t)s3 * 64) : (x2 + (size_t)(s3 - N) * 64);
        const float* r4 = (s4 < N) ? (x1 + (size_t)s4 * 64) : (x2 + (size_t)(s4 - N) * 64);
        const float* r5 = (s5 < N) ? (x1 + (size_t)s5 * 64) : (x2 + (size_t)(s5 - N) * 64);
        const float* r6 = (s6 < N) ? (x1 + (size_t)s6 * 64) : (x2 + (size_t)(s6 - N) * 64);
        const float* r7 = (s7 < N) ? (x1 + (size_t)s7 * 64) : (x2 + (size_t)(s7 - N) * 64);
        float v0 = dinv[s0] * r0[lane];
        float v1 = dinv[s1] * r1[lane];
        float v2 = dinv[s2] * r2[lane];
        float v3 = dinv[s3] * r3[lane];
        float v4 = dinv[s4] * r4[lane];
        float v5 = dinv[s5] * r5[lane];
        float v6 = dinv[s6] * r6[lane];
        float v7 = dinv[s7] * r7[lane];
        acc += ((v0 + v1) + (v2 + v3)) + ((v4 + v5) + (v6 + v7));
    }
    if (e < end) {  // masked batch: keeps up to 7 gathers in flight
#pragma unroll
        for (int j = 0; j < 7; ++j) {
            int a = e + j;
            bool vld = a < end;
            int s = csr[vld ? a : beg];
            float wt = vld ? dinv[s] : 0.f;
            const float* r = (s < N) ? (x1 + (size_t)s * 64) : (x2 + (size_t)(s - N) * 64);
            acc += wt * r[lane];
        }
    }
    unsigned short h = f2bf(acc);
    Shi[(size_t)w * 64 + lane] = h;
    Slo[(size_t)w * 64 + lane] = f2bf(acc - bf2f(h));
}

// ------- Layers 1-2 aggregation: input f32 (pre-scaled), output split bf16 -------

__global__ void agg128_kernel(const float* __restrict__ Xf, const int* __restrict__ rowptr,
                              const int* __restrict__ csr,
                              unsigned short* __restrict__ Shi, unsigned short* __restrict__ Slo,
                              int NN) {
    int w = blockIdx.x * (blockDim.x >> 6) + (threadIdx.x >> 6);
    int lane = threadIdx.x & 63;
    if (w >= NN) return;
    const float2* X = (const float2*)Xf;
    int beg = rowptr[w], end = rowptr[w + 1];
    float2 self = X[(size_t)w * 64 + lane];
    float ax = self.x, ay = self.y;
    int e = beg;
    int full_end = beg + ((end - beg) & ~7);
    for (; e < full_end; e += 8) {
        int s0 = csr[e], s1 = csr[e + 1], s2 = csr[e + 2], s3 = csr[e + 3];
        int s4 = csr[e + 4], s5 = csr[e + 5], s6 = csr[e + 6], s7 = csr[e + 7];
        float2 v0 = X[(size_t)s0 * 64 + lane];
        float2 v1 = X[(size_t)s1 * 64 + lane];
        float2 v2 = X[(size_t)s2 * 64 + lane];
        float2 v3 = X[(size_t)s3 * 64 + lane];
        float2 v4 = X[(size_t)s4 * 64 + lane];
        float2 v5 = X[(size_t)s5 * 64 + lane];
        float2 v6 = X[(size_t)s6 * 64 + lane];
        float2 v7 = X[(size_t)s7 * 64 + lane];
        ax += ((v0.x + v1.x) + (v2.x + v3.x)) + ((v4.x + v5.x) + (v6.x + v7.x));
        ay += ((v0.y + v1.y) + (v2.y + v3.y)) + ((v4.y + v5.y) + (v6.y + v7.y));
    }
    if (e < end) {
#pragma unroll
        for (int j = 0; j < 7; ++j) {
            int a = e + j;
            bool vld = a < end;
            int s = csr[vld ? a : beg];
            float m = vld ? 1.f : 0.f;
            float2 v = X[(size_t)s * 64 + lane];
            ax += m * v.x; ay += m * v.y;
        }
    }
    unsigned short hx = f2bf(ax), hy = f2bf(ay);
    ushort2 H; H.x = hx; H.y = hy;
    ushort2 L; L.x = f2bf(ax - bf2f(hx)); L.y = f2bf(ay - bf2f(hy));
    *reinterpret_cast<ushort2*>(Shi + (size_t)w * 128 + 2 * lane) = H;
    *reinterpret_cast<ushort2*>(Slo + (size_t)w * 128 + 2 * lane) = L;
}

// ---- MFMA GEMM: C[r] = po(r)*relu(dinv[r]*(A@W)[r] + bias), A = Ah+Al (split bf16) ----
// Block: 512 threads = 8 waves, BM=128 rows staged in LDS; wave w owns cols [16w,16w+16).

template <int K>
__global__ __launch_bounds__(512) void gemm_mfma(const unsigned short* __restrict__ Ah,
                                                 const unsigned short* __restrict__ Al,
                                                 const unsigned short* __restrict__ WhT,
                                                 const unsigned short* __restrict__ WlT,
                                                 const float* __restrict__ bias,
                                                 const float* __restrict__ dinv, int post,
                                                 float* __restrict__ C, int M) {
    const int LDA = K + 8;                       // pad: 2-way-max bank conflicts
    __shared__ unsigned short lds[2 * 128 * LDA];
    unsigned short* ldsH = lds;
    unsigned short* ldsL = lds + 128 * LDA;

    int t = threadIdx.x;
    int lane = t & 63, wid = t >> 6;
    int c16 = lane & 15, kq = (lane >> 4) * 8;
    int row0 = blockIdx.x * 128;

    // W fragments for this wave's 16-col tile, all K, hi+lo (from global, once).
    bf16x8 wh[K / 32], wl[K / 32];
    {
        int col = wid * 16 + c16;
#pragma unroll
        for (int ks = 0; ks < K / 32; ++ks) {
            wh[ks] = *reinterpret_cast<const bf16x8*>(WhT + (size_t)col * K + ks * 32 + kq);
            wl[ks] = *reinterpret_cast<const bf16x8*>(WlT + (size_t)col * K + ks * 32 + kq);
        }
    }

    // Stage A hi/lo tile: 128 rows x K bf16 each.
    const int CH = 128 * K / 8;  // 16B chunks per array
    for (int c = t; c < CH; c += 512) {
        int row = c / (K / 8), kb = c % (K / 8);
        int gr = row0 + row; if (gr >= M) gr = M - 1;
        *reinterpret_cast<bf16x8*>(ldsH + row * LDA + kb * 8) =
            *reinterpret_cast<const bf16x8*>(Ah + (size_t)gr * K + kb * 8);
        *reinterpret_cast<bf16x8*>(ldsL + row * LDA + kb * 8) =
            *reinterpret_cast<const bf16x8*>(Al + (size_t)gr * K + kb * 8);
    }
    __syncthreads();

    float bb = bias[wid * 16 + c16];
#pragma unroll
    for (int rt = 0; rt < 8; ++rt) {
        f32x4 acc = {0.f, 0.f, 0.f, 0.f};
        int abase = (rt * 16 + c16) * LDA + kq;
#pragma unroll
        for (int ks = 0; ks < K / 32; ++ks) {
            bf16x8 ah = *reinterpret_cast<const bf16x8*>(ldsH + abase + ks * 32);
            bf16x8 al = *reinterpret_cast<const bf16x8*>(ldsL + abase + ks * 32);
            acc = __builtin_amdgcn_mfma_f32_16x16x32_bf16(ah, wh[ks], acc, 0, 0, 0);
            acc = __builtin_amdgcn_mfma_f32_16x16x32_bf16(ah, wl[ks], acc, 0, 0, 0);
            acc = __builtin_amdgcn_mfma_f32_16x16x32_bf16(al, wh[ks], acc, 0, 0, 0);
        }
        // C/D layout: col = lane&15, row = (lane>>4)*4 + r   [m89-verified]
#pragma unroll
        for (int r = 0; r < 4; ++r) {
            int gr = row0 + rt * 16 + (lane >> 4) * 4 + r;
            if (gr < M) {
                float d = dinv[gr];
                float po = post ? d : 1.0f;
                float v = fmaxf(acc[r] * d + bb, 0.f) * po;
                C[(size_t)gr * 128 + wid * 16 + c16] = v;
            }
        }
    }
}

// ---------------- Final FC ----------------

__global__ void fc_kernel(const float* __restrict__ H3, const int* __restrict__ label,
                          const float* __restrict__ fcW, const float* __restrict__ fcb,
                          float* __restrict__ out, int P, int N) {
    int w = blockIdx.x * (blockDim.x >> 6) + (threadIdx.x >> 6);
    int lane = threadIdx.x & 63;
    if (w >= P) return;
    int l0 = label[2 * w], l1 = label[2 * w + 1] + N;
    float xl0 = H3[(size_t)l0 * 128 + lane];
    float xl1 = H3[(size_t)l0 * 128 + 64 + lane];
    float xr0 = H3[(size_t)l1 * 128 + lane];
    float xr1 = H3[(size_t)l1 * 128 + 64 + lane];
    float a0 = xl0 * fcW[lane * 2]             + xl1 * fcW[(64 + lane) * 2]
             + xr0 * fcW[(128 + lane) * 2]     + xr1 * fcW[(192 + lane) * 2];
    float a1 = xl0 * fcW[lane * 2 + 1]         + xl1 * fcW[(64 + lane) * 2 + 1]
             + xr0 * fcW[(128 + lane) * 2 + 1] + xr1 * fcW[(192 + lane) * 2 + 1];
#pragma unroll
    for (int o = 32; o; o >>= 1) {
        a0 += __shfl_xor(a0, o);
        a1 += __shfl_xor(a1, o);
    }
    if (lane == 0) {
        out[2 * w]     = fmaxf(a0 + fcb[0], 0.f);
        out[2 * w + 1] = fmaxf(a1 + fcb[1], 0.f);
    }
}

// ---------------- launch ----------------

extern "C" void kernel_launch(void* const* d_in, const int* in_sizes, int n_in,
                              void* d_out, int out_size, void* d_ws, size_t ws_size,
                              hipStream_t stream) {
    const float* x1   = (const float*)d_in[0];
    const int*   e1   = (const int*)d_in[1];
    const float* x2   = (const float*)d_in[2];
    const int*   e2   = (const int*)d_in[3];
    const int*   label= (const int*)d_in[4];
    const float* W0   = (const float*)d_in[5];
    const float* b0   = (const float*)d_in[6];
    const float* W1   = (const float*)d_in[7];
    const float* b1   = (const float*)d_in[8];
    const float* W2   = (const float*)d_in[9];
    const float* b2   = (const float*)d_in[10];
    const float* fcW  = (const float*)d_in[11];
    const float* fcb  = (const float*)d_in[12];
    float* out = (float*)d_out;

    const int N = in_sizes[0] / 64;
    const int E = in_sizes[1] / 2;
    const int P = in_sizes[4] / 2;
    const int NN = 2 * N;
    const int NB = (NN + 255) / 256;

    char* ws = (char*)d_ws;
    size_t off = 0;
    auto alloc = [&](size_t bytes) -> void* {
        void* p = ws + off;
        off += (bytes + 255) & ~(size_t)255;
        return p;
    };
    int*   cnt      = (int*)alloc((size_t)NN * 4);
    int*   rowptr   = (int*)alloc((size_t)(NN + 1) * 4);
    float* dinv     = (float*)alloc((size_t)NN * 4);
    int*   csr      = (int*)alloc((size_t)2 * E * 4);
    int*   blockSums= (int*)alloc((size_t)NB * 4);
    int*   blockOff = (int*)alloc((size_t)NB * 4);
    unsigned short* Shi = (unsigned short*)alloc((size_t)NN * 128 * 2);
    unsigned short* Slo = (unsigned short*)alloc((size_t)NN * 128 * 2);
    float* Xs       = (float*)alloc((size_t)NN * 128 * 4);
    unsigned short* W0h = (unsigned short*)alloc(64 * 128 * 2);
    unsigned short* W0l = (unsigned short*)alloc(64 * 128 * 2);
    unsigned short* W1h = (unsigned short*)alloc(128 * 128 * 2);
    unsigned short* W1l = (unsigned short*)alloc(128 * 128 * 2);
    unsigned short* W2h = (unsigned short*)alloc(128 * 128 * 2);
    unsigned short* W2l = (unsigned short*)alloc(128 * 128 * 2);

    const int GB = (NN + 127) / 128;  // gemm blocks

    prep_weights<<<3, 256, 0, stream>>>(W0, W1, W2, W0h, W0l, W1h, W1l, W2h, W2l);

    // CSR build (once, union graph)
    hipMemsetAsync(cnt, 0, (size_t)NN * 4, stream);
    histU_kernel<<<(2 * E + 255) / 256, 256, 0, stream>>>(e1 + E, e2 + E, cnt, E, N);
    block_reduce_kernel<<<NB, 256, 0, stream>>>(cnt, dinv, blockSums, NN);
    scan_sums_kernel<<<1, 1024, 0, stream>>>(blockSums, blockOff, NB, rowptr, NN);
    scan_write_kernel<<<NB, 256, 0, stream>>>(cnt, blockOff, rowptr, NN);
    placeU_kernel<<<(2 * E + 255) / 256, 256, 0, stream>>>(e1, e1 + E, e2, e2 + E,
                                                           rowptr, cnt, csr, E, N);
    // layer 0
    agg64U_kernel<<<(NN + 3) / 4, 256, 0, stream>>>(x1, x2, rowptr, csr, dinv, Shi, Slo, NN, N);
    gemm_mfma<64><<<GB, 512, 0, stream>>>(Shi, Slo, W0h, W0l, b0, dinv, 1, Xs, NN);
    // layer 1
    agg128_kernel<<<(NN + 3) / 4, 256, 0, stream>>>(Xs, rowptr, csr, Shi, Slo, NN);
    gemm_mfma<128><<<GB, 512, 0, stream>>>(Shi, Slo, W1h, W1l, b1, dinv, 1, Xs, NN);
    // layer 2 (no post-scale): H3 lands in Xs
    agg128_kernel<<<(NN + 3) / 4, 256, 0, stream>>>(Xs, rowptr, csr, Shi, Slo, NN);
    gemm_mfma<128><<<GB, 512, 0, stream>>>(Shi, Slo, W2h, W2l, b2, dinv, 0, Xs, NN);

    fc_kernel<<<(P + 3) / 4, 256, 0, stream>>>(Xs, label, fcW, fcb, out, P, N);
}